// Round 1
// 72.702 us; speedup vs baseline: 1.0125x; 1.0125x over previous
//
#include <hip/hip_runtime.h>

// NNLoss: bidirectional Chamfer NN-L1. B=16, N=M=2048, D=2, scalar f32 out.
//
// R11: model revision — gfx950 has NO packed-f32 FLOP advantage (157.3 TF
// peak == scalar v_fma_f32 rate => v_pk_fma_f32 occupies 4 cyc/wave64 vs
// 2 for scalar). Re-costed scan: ~7.15us VALU/SIMD + ~3.4us DS = measured
// ~13us. The "2x model gap" was pk half-rate; scan is VALU-CYCLE-bound and
// DS has slack (explains R5 neutrality). This round: VALU diet, trade into
// DS slack:
//  - zs4: t^2 = fma(x,x,y*y) precomputed once at staging, broadcast-read
//    (saves 32 VALU-cyc/octet/wave for +2 uniform ds_read_b128)
//  - octet min-tracking: 8 points per tracked index; per q per octet:
//    8 pk_fma + 7 fminf (min3-fusable) + 1 cmp/2 sel = ~46-52 cyc vs 56
//  - recovery: reload octet (incl. zs4 -> bit-identical), first-match of 8
//    by descending overwrite => earliest index; strict-< across octets
//    keeps earliest octet => global first-index argmin, exact as before
// Cross-segment merge unchanged: packed u64 (monotone f bits | idx) min.
// Predicted: dur 73.6 -> ~71.5us. If neutral: scan is latency-bound ->
// next round 2 blocks/CU (G=128). LDS now 56.2KB (still < 64KB).

typedef float v2f __attribute__((ext_vector_type(2)));
typedef float v4f __attribute__((ext_vector_type(4)));

constexpr int B      = 16;
constexpr int NPTS   = 2048;
constexpr int BLK    = 1024;
constexpr int G      = 256;          // queries per block
constexpr int S      = 16;           // db segments (one per wave)
constexpr int QPT    = 4;            // queries per thread
constexpr int SEGLEN = NPTS / S;     // 128 points per segment
constexpr int QUADS  = SEGLEN / 4;   // 32 point-quads per segment
constexpr int OCTS   = SEGLEN / 8;   // 16 point-octets per segment
constexpr int NBLK   = 2 * B * (NPTS / G);  // 256 blocks

__global__ __launch_bounds__(BLK) void nn_main(
    const float* __restrict__ preds, const float* __restrict__ targs,
    const float* __restrict__ subcoef, float* __restrict__ out)
{
    __shared__ v4f xs4[NPTS / 4];                  // 8 KB quad-packed x
    __shared__ v4f ys4[NPTS / 4];                  // 8 KB quad-packed y
    __shared__ v4f zs4[NPTS / 4];                  // 8 KB quad-packed t^2
    __shared__ unsigned long long cand[S * G];     // 32 KB candidates
    __shared__ float ssum[BLK / 64];

    const int blk  = blockIdx.x;
    const int dir  = blk >> 7;          // 0: preds->targs (subcoef), 1: reverse
    const int b    = (blk >> 3) & 15;
    const int tile = blk & 7;

    const float2* qb = reinterpret_cast<const float2*>(dir == 0 ? preds : targs)
                       + b * NPTS + tile * G;
    const float2* db = reinterpret_cast<const float2*>(dir == 0 ? targs : preds)
                       + b * NPTS;

    // Stage db as quad-packed SoA. Threads <512 build xs4; >=512 build ys4
    // AND zs4 (t^2, fma-rounded exactly as the scan previously computed it).
    const float4* db4 = reinterpret_cast<const float4*>(db);
    {
        const int j = threadIdx.x & 511;
        const float4 a = db4[2 * j];
        const float4 c = db4[2 * j + 1];
        if (threadIdx.x < 512) {
            xs4[j] = {a.x, a.z, c.x, c.z};
        } else {
            ys4[j] = {a.y, a.w, c.y, c.w};
            zs4[j] = {fmaf(a.x, a.x, a.y * a.y), fmaf(a.z, a.z, a.w * a.w),
                      fmaf(c.x, c.x, c.y * c.y), fmaf(c.z, c.z, c.w * c.w)};
        }
    }

    const int qslot = threadIdx.x & 63;   // query slot within wave
    const int seg   = threadIdx.x >> 6;   // one 128-point segment per wave

    // 4 register-resident queries, coefficients splatted for packed fma.
    v2f   m2x[QPT], m2y[QPT];
    float best[QPT];
    int   bj[QPT];                        // best octet (0..15)
    #pragma unroll
    for (int q = 0; q < QPT; ++q) {
        const float2 qp = qb[qslot + q * 64];
        const float ax = -2.0f * qp.x, ay = -2.0f * qp.y;
        m2x[q] = {ax, ax};
        m2y[q] = {ay, ay};
        best[q] = 3.402823466e+38f;
        bj[q] = 0;
    }
    __syncthreads();

    // Scan segment, 8 points per super-iter. f(t) = t^2 - 2 q.t (monotone in
    // d^2 per query; bit-identical across segments -> exact cross-seg merge).
    const v4f* xsp = xs4 + seg * QUADS;
    const v4f* ysp = ys4 + seg * QUADS;
    const v4f* zsp = zs4 + seg * QUADS;
    #pragma unroll 2
    for (int i = 0; i < OCTS; ++i) {
        const v4f X0 = xsp[2 * i],     Y0 = ysp[2 * i],     Z0 = zsp[2 * i];
        const v4f X1 = xsp[2 * i + 1], Y1 = ysp[2 * i + 1], Z1 = zsp[2 * i + 1];
        const v2f x0 = {X0.x, X0.y}, x1 = {X0.z, X0.w};
        const v2f x2 = {X1.x, X1.y}, x3 = {X1.z, X1.w};
        const v2f y0 = {Y0.x, Y0.y}, y1 = {Y0.z, Y0.w};
        const v2f y2 = {Y1.x, Y1.y}, y3 = {Y1.z, Y1.w};
        const v2f z0 = {Z0.x, Z0.y}, z1 = {Z0.z, Z0.w};
        const v2f z2 = {Z1.x, Z1.y}, z3 = {Z1.z, Z1.w};
        #pragma unroll
        for (int q = 0; q < QPT; ++q) {
            const v2f d0 = __builtin_elementwise_fma(
                m2x[q], x0, __builtin_elementwise_fma(m2y[q], y0, z0));
            const v2f d1 = __builtin_elementwise_fma(
                m2x[q], x1, __builtin_elementwise_fma(m2y[q], y1, z1));
            const v2f d2 = __builtin_elementwise_fma(
                m2x[q], x2, __builtin_elementwise_fma(m2y[q], y2, z2));
            const v2f d3 = __builtin_elementwise_fma(
                m2x[q], x3, __builtin_elementwise_fma(m2y[q], y3, z3));
            const float m01 = fminf(fminf(d0.x, d0.y), fminf(d1.x, d1.y));
            const float m23 = fminf(fminf(d2.x, d2.y), fminf(d3.x, d3.y));
            const float dm  = fminf(m01, m23);
            if (dm < best[q]) { best[q] = dm; bj[q] = i; }  // strict <
        }
    }

    // Exact index recovery: recompute the winning octet bit-identically
    // (zs4 re-read => identical t^2 bits) and take the FIRST in-octet index
    // whose distance equals best (descending overwrite => lowest wins).
    #pragma unroll
    for (int q = 0; q < QPT; ++q) {
        const v4f X0 = xsp[2 * bj[q]],     Y0 = ysp[2 * bj[q]],     Z0 = zsp[2 * bj[q]];
        const v4f X1 = xsp[2 * bj[q] + 1], Y1 = ysp[2 * bj[q] + 1], Z1 = zsp[2 * bj[q] + 1];
        const v2f x0 = {X0.x, X0.y}, x1 = {X0.z, X0.w};
        const v2f x2 = {X1.x, X1.y}, x3 = {X1.z, X1.w};
        const v2f y0 = {Y0.x, Y0.y}, y1 = {Y0.z, Y0.w};
        const v2f y2 = {Y1.x, Y1.y}, y3 = {Y1.z, Y1.w};
        const v2f z0 = {Z0.x, Z0.y}, z1 = {Z0.z, Z0.w};
        const v2f z2 = {Z1.x, Z1.y}, z3 = {Z1.z, Z1.w};
        const v2f d0 = __builtin_elementwise_fma(
            m2x[q], x0, __builtin_elementwise_fma(m2y[q], y0, z0));
        const v2f d1 = __builtin_elementwise_fma(
            m2x[q], x1, __builtin_elementwise_fma(m2y[q], y1, z1));
        const v2f d2 = __builtin_elementwise_fma(
            m2x[q], x2, __builtin_elementwise_fma(m2y[q], y2, z2));
        const v2f d3 = __builtin_elementwise_fma(
            m2x[q], x3, __builtin_elementwise_fma(m2y[q], y3, z3));
        int off = 7;
        if (d3.x == best[q]) off = 6;
        if (d2.y == best[q]) off = 5;
        if (d2.x == best[q]) off = 4;
        if (d1.y == best[q]) off = 3;
        if (d1.x == best[q]) off = 2;
        if (d0.y == best[q]) off = 1;
        if (d0.x == best[q]) off = 0;
        const int idx = seg * SEGLEN + 8 * bj[q] + off;
        unsigned int fb = __float_as_uint(best[q]);
        fb ^= 0x80000000u | (unsigned int)((int)fb >> 31);  // total-order map
        cand[seg * G + qslot + q * 64] =
            ((unsigned long long)fb << 32) | (unsigned int)idx;
    }
    __syncthreads();

    // First G threads: u64-min over 16 segment candidates = exact argmin.
    float val = 0.0f;
    if (threadIdx.x < G) {
        unsigned long long bp = cand[threadIdx.x];
        #pragma unroll
        for (int s = 1; s < S; ++s) {
            const unsigned long long v = cand[s * G + threadIdx.x];
            bp = v < bp ? v : bp;
        }
        const int idx = (int)(unsigned int)bp;
        const float2 qp = qb[threadIdx.x];
        const float2 tp = db[idx];            // scattered 8B, cache-hot
        float sx = 1.0f, sy = 1.0f;
        if (dir == 0) { sx = subcoef[0]; sy = subcoef[1]; }
        val = fabsf(qp.x - tp.x) * sx + fabsf(qp.y - tp.y) * sy;
    }

    // Block reduction, one atomic per block onto poisoned d_out (harmless).
    #pragma unroll
    for (int off = 32; off > 0; off >>= 1)
        val += __shfl_down(val, off, 64);
    if ((threadIdx.x & 63) == 0) ssum[threadIdx.x >> 6] = val;
    __syncthreads();
    if (threadIdx.x == 0) {
        float s = ssum[0];
        #pragma unroll
        for (int w = 1; w < BLK / 64; ++w) s += ssum[w];
        atomicAdd(out, s);   // device-scope: coherent across XCDs
    }
}

extern "C" void kernel_launch(void* const* d_in, const int* in_sizes, int n_in,
                              void* d_out, int out_size, void* d_ws, size_t ws_size,
                              hipStream_t stream) {
    const float* preds   = (const float*)d_in[0];
    const float* targs   = (const float*)d_in[1];
    const float* subcoef = (const float*)d_in[2];
    float* out = (float*)d_out;

    nn_main<<<NBLK, BLK, 0, stream>>>(preds, targs, subcoef, out);
}